// Round 4
// baseline (8726.588 us; speedup 1.0000x reference)
//
#include <hip/hip_runtime.h>
#include <cstdint>

__device__ __forceinline__ float sigm(float x) { return 1.f / (1.f + __expf(-x)); }
__device__ __forceinline__ float tanh_(float x) { return 1.f - 2.f / (1.f + __expf(2.f * x)); }

__device__ __forceinline__ float dot4(float4 a, float4 b) {
    return fmaf(a.x, b.x, fmaf(a.y, b.y, fmaf(a.z, b.z, a.w * b.w)));
}

// ---------------- init: copy fp32 states into ws ----------------
__global__ __launch_bounds__(256) void k_init(const float* __restrict__ h0in,
                                              const float* __restrict__ c0in,
                                              const float* __restrict__ feedin,
                                              float* h0A, float* h1A, float* c0f, float* c1f,
                                              float* feed) {
    int i = blockIdx.x * 256 + threadIdx.x;  // 128*256 = 32768 = B*H
    h0A[i] = h0in[i];
    h1A[i] = h0in[32768 + i];
    c0f[i] = c0in[i];
    c1f[i] = c0in[32768 + i];
    feed[i] = feedin[i];
}

// ---------------- LSTM layer 0: one block per hidden index hh, K=1536 ----------
// thread (b = tid>>2, g = tid&3) computes gate row g*512+hh for batch b
__global__ __launch_bounds__(256) void k_lstm0(int t, const int* __restrict__ toks,
                                               const float* __restrict__ emb,
                                               const float* __restrict__ Wih0,
                                               const float* __restrict__ Whh0,
                                               const float* __restrict__ bih0,
                                               const float* __restrict__ bhh0,
                                               const float* __restrict__ feed,
                                               const float* __restrict__ h0in,
                                               float* __restrict__ h0out,
                                               float* __restrict__ c0f,
                                               float* __restrict__ outHf,
                                               float* __restrict__ outCf) {
    __shared__ float gx[64][4];
    int hh = blockIdx.x;  // [0,512)
    int b = threadIdx.x >> 2, g = threadIdx.x & 3;
    const float4* wr0 = (const float4*)(Wih0 + (size_t)(g * 512 + hh) * 1024); // [emb|feed]
    const float4* wr1 = (const float4*)(Whh0 + (size_t)(g * 512 + hh) * 512);  // h
    int tok = toks[t * 64 + b];
    const float4* x0 = (const float4*)(emb + (size_t)tok * 512);
    const float4* x1 = (const float4*)(feed + (size_t)b * 512);
    const float4* x2 = (const float4*)(h0in + (size_t)b * 512);
    float acc = 0.f;
    for (int kb = 0; kb < 128; kb++) acc += dot4(wr0[kb], x0[kb]);
    for (int kb = 0; kb < 128; kb++) acc += dot4(wr0[128 + kb], x1[kb]);
    for (int kb = 0; kb < 128; kb++) acc += dot4(wr1[kb], x2[kb]);
    gx[b][g] = acc;
    __syncthreads();
    if (threadIdx.x < 64) {
        int bb = threadIdx.x;
        float gi = gx[bb][0] + bih0[hh] + bhh0[hh];
        float gf = gx[bb][1] + bih0[512 + hh] + bhh0[512 + hh];
        float gg = gx[bb][2] + bih0[1024 + hh] + bhh0[1024 + hh];
        float go = gx[bb][3] + bih0[1536 + hh] + bhh0[1536 + hh];
        float c = c0f[bb * 512 + hh];
        float cn = sigm(gf) * c + sigm(gi) * tanh_(gg);
        float hn = sigm(go) * tanh_(cn);
        c0f[bb * 512 + hh] = cn;
        h0out[bb * 512 + hh] = hn;
        if (t == 31) { outHf[bb * 512 + hh] = hn; outCf[bb * 512 + hh] = cn; }
    }
}

// ---------------- LSTM layer 1: K = 1024 (h0n | h1) ----------------
__global__ __launch_bounds__(256) void k_lstm1(int t, const float* __restrict__ Wih1,
                                               const float* __restrict__ Whh1,
                                               const float* __restrict__ bih1,
                                               const float* __restrict__ bhh1,
                                               const float* __restrict__ h0n,
                                               const float* __restrict__ h1in,
                                               float* __restrict__ h1out,
                                               float* __restrict__ c1f,
                                               float* __restrict__ outHf,
                                               float* __restrict__ outCf) {
    __shared__ float gx[64][4];
    int hh = blockIdx.x;
    int b = threadIdx.x >> 2, g = threadIdx.x & 3;
    const float4* wr0 = (const float4*)(Wih1 + (size_t)(g * 512 + hh) * 512);
    const float4* wr1 = (const float4*)(Whh1 + (size_t)(g * 512 + hh) * 512);
    const float4* x0 = (const float4*)(h0n + (size_t)b * 512);
    const float4* x1 = (const float4*)(h1in + (size_t)b * 512);
    float acc = 0.f;
    for (int kb = 0; kb < 128; kb++) acc += dot4(wr0[kb], x0[kb]);
    for (int kb = 0; kb < 128; kb++) acc += dot4(wr1[kb], x1[kb]);
    gx[b][g] = acc;
    __syncthreads();
    if (threadIdx.x < 64) {
        int bb = threadIdx.x;
        float gi = gx[bb][0] + bih1[hh] + bhh1[hh];
        float gf = gx[bb][1] + bih1[512 + hh] + bhh1[512 + hh];
        float gg = gx[bb][2] + bih1[1024 + hh] + bhh1[1024 + hh];
        float go = gx[bb][3] + bih1[1536 + hh] + bhh1[1536 + hh];
        float c = c1f[bb * 512 + hh];
        float cn = sigm(gf) * c + sigm(gi) * tanh_(gg);
        float hn = sigm(go) * tanh_(cn);
        c1f[bb * 512 + hh] = cn;
        h1out[bb * 512 + hh] = hn;
        if (t == 31) { outHf[bb * 512 + hh] = hn; outCf[bb * 512 + hh] = cn; }
    }
}

// ---------------- query: q[b,i] = sum_k h1[b,k] * Wa[i,k] ----------------
__global__ __launch_bounds__(256) void k_query(const float* __restrict__ Wa,
                                               const float* __restrict__ h1n,
                                               float* __restrict__ qbuf) {
    int b = threadIdx.x >> 2, ii = threadIdx.x & 3;
    int i = blockIdx.x * 4 + ii;  // 128 blocks -> i in [0,512)
    const float4* wr = (const float4*)(Wa + (size_t)i * 512);
    const float4* xr = (const float4*)(h1n + (size_t)b * 512);
    float acc = 0.f;
    for (int kb = 0; kb < 128; kb++) acc += dot4(wr[kb], xr[kb]);
    qbuf[b * 512 + i] = acc;
}

// ---------------- attention: scores -> softmax -> cvec. One block per b --------
__global__ __launch_bounds__(256) void k_attn(int t, const float* __restrict__ ctx,
                                              const float* __restrict__ qbuf,
                                              float* __restrict__ cvec,
                                              float* __restrict__ outAtt) {
    __shared__ float qL[512];
    __shared__ float sc4[64][4];
    __shared__ float pl[64];
    int b = blockIdx.x, tid = threadIdx.x;
    for (int i = tid; i < 512; i += 256) qL[i] = qbuf[b * 512 + i];
    __syncthreads();
    // scores[s] = sum_i q[i] * ctx[s,b,i]
    {
        int s = tid >> 2, part = tid & 3;
        const float4* row = (const float4*)(ctx + ((size_t)s * 64 + b) * 512 + part * 128);
        float acc = 0.f;
        for (int kb = 0; kb < 32; kb++) {
            float4 cv = row[kb];
            int k = part * 128 + kb * 4;
            acc = fmaf(cv.x, qL[k], acc);
            acc = fmaf(cv.y, qL[k + 1], acc);
            acc = fmaf(cv.z, qL[k + 2], acc);
            acc = fmaf(cv.w, qL[k + 3], acc);
        }
        sc4[s][part] = acc;
    }
    __syncthreads();
    if (tid < 64) {
        int s = tid;
        float v = sc4[s][0] + sc4[s][1] + sc4[s][2] + sc4[s][3];
        float m = v;
        for (int off = 32; off; off >>= 1) m = fmaxf(m, __shfl_xor(m, off));
        float e = __expf(v - m);
        float sum = e;
        for (int off = 32; off; off >>= 1) sum += __shfl_xor(sum, off);
        float p = e / sum;
        pl[s] = p;
        outAtt[((size_t)t * 64 + b) * 64 + s] = p;
    }
    __syncthreads();
    // cvec[h] = sum_s p[s] * ctx[s,b,h]
    for (int h = tid; h < 512; h += 256) {
        float acc = 0.f;
        for (int s = 0; s < 64; s++)
            acc = fmaf(pl[s], ctx[((size_t)s * 64 + b) * 512 + h], acc);
        cvec[b * 512 + h] = acc;
    }
}

// ---------------- out projection: attn_h = tanh([cvec|h1n] @ Wout^T) -----------
__global__ __launch_bounds__(256) void k_out(int t, const float* __restrict__ Wout,
                                             const float* __restrict__ cvec,
                                             const float* __restrict__ h1n,
                                             float* __restrict__ feed,
                                             float* __restrict__ outMain,
                                             float* __restrict__ outFeedf) {
    int b = threadIdx.x >> 2, oi = threadIdx.x & 3;
    int o = blockIdx.x * 4 + oi;  // 128 blocks -> o in [0,512)
    const float4* wr = (const float4*)(Wout + (size_t)o * 1024);
    const float4* x0 = (const float4*)(cvec + (size_t)b * 512);
    const float4* x1 = (const float4*)(h1n + (size_t)b * 512);
    float acc = 0.f;
    for (int kb = 0; kb < 128; kb++) acc += dot4(wr[kb], x0[kb]);
    for (int kb = 0; kb < 128; kb++) acc += dot4(wr[128 + kb], x1[kb]);
    float ah = tanh_(acc);
    outMain[((size_t)t * 64 + b) * 512 + o] = ah;
    feed[b * 512 + o] = ah;
    if (t == 31) outFeedf[b * 512 + o] = ah;
}

extern "C" void kernel_launch(void* const* d_in, const int* in_sizes, int n_in,
                              void* d_out, int out_size, void* d_ws, size_t ws_size,
                              hipStream_t stream) {
    const int*   toks  = (const int*)d_in[0];
    /* d_in[1] = src: unused by reference */
    const float* ctx   = (const float*)d_in[2];
    const float* h0i   = (const float*)d_in[3];
    const float* c0i   = (const float*)d_in[4];
    const float* feedi = (const float*)d_in[5];
    const float* emb   = (const float*)d_in[6];
    const float* Wih0  = (const float*)d_in[7];
    const float* Whh0  = (const float*)d_in[8];
    const float* bih0  = (const float*)d_in[9];
    const float* bhh0  = (const float*)d_in[10];
    const float* Wih1  = (const float*)d_in[11];
    const float* Whh1  = (const float*)d_in[12];
    const float* bih1  = (const float*)d_in[13];
    const float* bhh1  = (const float*)d_in[14];
    const float* Wa    = (const float*)d_in[15];
    const float* Wout  = (const float*)d_in[16];

    // workspace: 9 x 131072 B = 1,179,648 B (all fp32 [64][512] buffers)
    char* ws = (char*)d_ws;
    float* c0f  = (float*)(ws);
    float* c1f  = (float*)(ws + 131072);
    float* h0A  = (float*)(ws + 262144);
    float* h0B  = (float*)(ws + 393216);
    float* h1A  = (float*)(ws + 524288);
    float* h1B  = (float*)(ws + 655360);
    float* feed = (float*)(ws + 786432);
    float* cvec = (float*)(ws + 917504);
    float* qbuf = (float*)(ws + 1048576);

    float* out      = (float*)d_out;
    float* outMain  = out;             // [T,B,H] = 1048576
    float* outAtt   = out + 1048576;   // [T,B,S] = 131072
    float* outHf    = out + 1179648;   // [L,B,H] = 65536
    float* outCf    = out + 1245184;   // [L,B,H] = 65536
    float* outFeedf = out + 1310720;   // [B,H]   = 32768

    hipLaunchKernelGGL(k_init, dim3(128), dim3(256), 0, stream,
                       h0i, c0i, feedi, h0A, h1A, c0f, c1f, feed);

    for (int t = 0; t < 32; t++) {
        float* h0in  = (t & 1) ? h0B : h0A;
        float* h0out = (t & 1) ? h0A : h0B;
        float* h1in  = (t & 1) ? h1B : h1A;
        float* h1out = (t & 1) ? h1A : h1B;
        hipLaunchKernelGGL(k_lstm0, dim3(512), dim3(256), 0, stream,
                           t, toks, emb, Wih0, Whh0, bih0, bhh0, feed, h0in, h0out, c0f,
                           outHf, outCf);
        hipLaunchKernelGGL(k_lstm1, dim3(512), dim3(256), 0, stream,
                           t, Wih1, Whh1, bih1, bhh1, h0out, h1in, h1out, c1f,
                           outHf + 32768, outCf + 32768);
        hipLaunchKernelGGL(k_query, dim3(128), dim3(256), 0, stream,
                           Wa, h1out, qbuf);
        hipLaunchKernelGGL(k_attn, dim3(64), dim3(256), 0, stream,
                           t, ctx, qbuf, cvec, outAtt);
        hipLaunchKernelGGL(k_out, dim3(128), dim3(256), 0, stream,
                           t, Wout, cvec, h1out, feed, outMain, outFeedf);
    }
}

// Round 5
// 3064.659 us; speedup vs baseline: 2.8475x; 2.8475x over previous
//
#include <hip/hip_runtime.h>
#include <cstdint>

__device__ __forceinline__ float sigm(float x) { return 1.f / (1.f + __expf(-x)); }
__device__ __forceinline__ float tanh_(float x) { return 1.f - 2.f / (1.f + __expf(2.f * x)); }

__device__ __forceinline__ void fma4(float4& a, float s, const float4& x) {
    a.x = fmaf(s, x.x, a.x); a.y = fmaf(s, x.y, a.y);
    a.z = fmaf(s, x.z, a.z); a.w = fmaf(s, x.w, a.w);
}

// ---------------- init: states into transposed [h][b] layout ----------------
__global__ __launch_bounds__(256) void k_init(const float* __restrict__ h0i,
                                              const float* __restrict__ c0i,
                                              const float* __restrict__ feedi,
                                              float* h0T, float* h1T, float* c0T, float* c1T,
                                              float* feedT) {
    int t = blockIdx.x * 256 + threadIdx.x;  // 32768 = 512*64
    int hh = t >> 6, b = t & 63;
    h0T[t]   = h0i[b * 512 + hh];
    h1T[t]   = h0i[32768 + b * 512 + hh];
    c0T[t]   = c0i[b * 512 + hh];
    c1T[t]   = c0i[32768 + b * 512 + hh];
    feedT[t] = feedi[b * 512 + hh];
}

// ---------------- generic K-split partial GEMM ----------------
// Out[g, b] partial = sum_{k in split} W[g,k] * X[k,b]
// W = concat(W0[NG][ldK0] | W1[NG][ldK1]) along k, boundary at KW0.
// X assembled from 512-wide segments s0T/s1T/s2T, each transposed [512 k][64 b].
// If s0T == nullptr: segment 0 is an embedding gather: emb[toks[t*64+b]][k].
// grid (NG/64, Ksplit); block 256. Kspl multiple of 128.
__global__ __launch_bounds__(256, 2) void k_gemmp(
    const float* __restrict__ W0, int ldK0, int KW0,
    const float* __restrict__ W1, int ldK1,
    float* __restrict__ partial, int NG,
    const float* __restrict__ s0T, const float* __restrict__ s1T,
    const float* __restrict__ s2T,
    const float* __restrict__ emb, const int* __restrict__ toks, int tstep,
    int Kspl) {
    __shared__ float XT[128 * 68];  // [k 0..127][b 0..63], stride 68 (2-way conflicts max)
    int g0 = blockIdx.x * 64;
    int kbase = blockIdx.y * Kspl;
    float* pout = partial + (size_t)blockIdx.y * NG * 64;
    int tid = threadIdx.x;
    int i0 = (tid >> 4) * 4;   // gate sub-offset (0..60)
    int b0 = (tid & 15) * 4;   // batch offset (0..60)
    float4 acc[4] = {};
    int nchunk = Kspl >> 7;
    for (int kc = 0; kc < nchunk; kc++) {
        int kg = kbase + kc * 128;       // 128-aligned; never straddles a 512-segment
        int seg = kg >> 9, ko = kg & 511;
        __syncthreads();
        if (seg == 0 && s0T == nullptr) {
            // embedding gather + transpose
            int b = tid >> 2, q = tid & 3;
            const float* er = emb + (size_t)toks[tstep * 64 + b] * 512 + ko;
#pragma unroll
            for (int j = 0; j < 8; j++) {
                int f4 = q + j * 4;  // 0..31
                float4 v = *(const float4*)(er + f4 * 4);
                int kl = f4 * 4;
                XT[(kl + 0) * 68 + b] = v.x;
                XT[(kl + 1) * 68 + b] = v.y;
                XT[(kl + 2) * 68 + b] = v.z;
                XT[(kl + 3) * 68 + b] = v.w;
            }
        } else {
            const float* sT = (seg == 0) ? s0T : (seg == 1) ? s1T : s2T;
            const float4* src = (const float4*)(sT + (size_t)ko * 64);
#pragma unroll
            for (int j = 0; j < 8; j++) {
                int f = tid + j * 256;   // 0..2047
                int k = f >> 4, bq = f & 15;
                *(float4*)&XT[k * 68 + bq * 4] = src[f];
            }
        }
        __syncthreads();
        // W chunk pointer (uniform per chunk)
        const float* wb;
        size_t wld;
        if (kg < KW0) { wb = W0 + kg; wld = (size_t)ldK0; }
        else          { wb = W1 + (kg - KW0); wld = (size_t)ldK1; }
        const float* wrow = wb + (size_t)(g0 + i0) * wld;
#pragma unroll 4
        for (int k4 = 0; k4 < 32; k4++) {
            float4 wv[4], xb[4];
#pragma unroll
            for (int i = 0; i < 4; i++)
                wv[i] = *(const float4*)(wrow + (size_t)i * wld + k4 * 4);
#pragma unroll
            for (int kk = 0; kk < 4; kk++)
                xb[kk] = *(const float4*)&XT[(k4 * 4 + kk) * 68 + b0];
#pragma unroll
            for (int i = 0; i < 4; i++) {
                fma4(acc[i], wv[i].x, xb[0]);
                fma4(acc[i], wv[i].y, xb[1]);
                fma4(acc[i], wv[i].z, xb[2]);
                fma4(acc[i], wv[i].w, xb[3]);
            }
        }
    }
#pragma unroll
    for (int i = 0; i < 4; i++)
        *(float4*)&pout[(size_t)(g0 + i0 + i) * 64 + b0] = acc[i];
}

// ---------------- cell: reduce partials + bias + LSTM activations ----------------
__global__ __launch_bounds__(256) void k_cell(const float* __restrict__ P, int nspl,
                                              const float* __restrict__ bih,
                                              const float* __restrict__ bhh,
                                              float* __restrict__ hT, float* __restrict__ cT,
                                              float* __restrict__ outHf,
                                              float* __restrict__ outCf, int tstep) {
    int t = blockIdx.x * 256 + threadIdx.x;  // 32768
    int hh = t >> 6, b = t & 63;
    float g[4];
#pragma unroll
    for (int gg = 0; gg < 4; gg++) {
        int gr = gg * 512 + hh;
        float v = bih[gr] + bhh[gr];
        for (int s = 0; s < nspl; s++) v += P[((size_t)s * 2048 + gr) * 64 + b];
        g[gg] = v;
    }
    float c = cT[t];
    float cn = sigm(g[1]) * c + sigm(g[0]) * tanh_(g[2]);
    float hn = sigm(g[3]) * tanh_(cn);
    cT[t] = cn;
    hT[t] = hn;
    if (tstep == 31) { outHf[b * 512 + hh] = hn; outCf[b * 512 + hh] = cn; }
}

// ---------------- attention: q-reduce, scores, softmax, cvec. One block per b ----
__global__ __launch_bounds__(256) void k_qattn(int tstep, const float* __restrict__ ctx,
                                               const float* __restrict__ qP, int nspl,
                                               float* __restrict__ cvecT,
                                               float* __restrict__ outAtt) {
    __shared__ float qL[512];
    __shared__ float sc4[64][4];
    __shared__ float pl[64];
    int b = blockIdx.x, tid = threadIdx.x;
    for (int i = tid; i < 512; i += 256) {
        float v = 0.f;
        for (int s = 0; s < nspl; s++) v += qP[((size_t)s * 512 + i) * 64 + b];
        qL[i] = v;
    }
    __syncthreads();
    {
        int s = tid >> 2, part = tid & 3;
        const float4* row = (const float4*)(ctx + ((size_t)s * 64 + b) * 512 + part * 128);
        float acc = 0.f;
        for (int kb = 0; kb < 32; kb++) {
            float4 cv = row[kb];
            int k = part * 128 + kb * 4;
            acc = fmaf(cv.x, qL[k], acc);
            acc = fmaf(cv.y, qL[k + 1], acc);
            acc = fmaf(cv.z, qL[k + 2], acc);
            acc = fmaf(cv.w, qL[k + 3], acc);
        }
        sc4[s][part] = acc;
    }
    __syncthreads();
    if (tid < 64) {
        int s = tid;
        float v = sc4[s][0] + sc4[s][1] + sc4[s][2] + sc4[s][3];
        float m = v;
        for (int off = 32; off; off >>= 1) m = fmaxf(m, __shfl_xor(m, off));
        float e = __expf(v - m);
        float sum = e;
        for (int off = 32; off; off >>= 1) sum += __shfl_xor(sum, off);
        float p = e / sum;
        pl[s] = p;
        outAtt[((size_t)tstep * 64 + b) * 64 + s] = p;
    }
    __syncthreads();
    for (int h = tid; h < 512; h += 256) {
        float acc = 0.f;
        for (int s = 0; s < 64; s++)
            acc = fmaf(pl[s], ctx[((size_t)s * 64 + b) * 512 + h], acc);
        cvecT[h * 64 + b] = acc;
    }
}

// ---------------- out reduce: tanh + outputs + next feed ----------------
__global__ __launch_bounds__(256) void k_outred(int tstep, const float* __restrict__ P,
                                                int nspl, float* __restrict__ feedT,
                                                float* __restrict__ outMain,
                                                float* __restrict__ outFeedf) {
    int t = blockIdx.x * 256 + threadIdx.x;  // 32768
    int o = t >> 6, b = t & 63;
    float v = 0.f;
    for (int s = 0; s < nspl; s++) v += P[((size_t)s * 512 + o) * 64 + b];
    float ah = tanh_(v);
    outMain[((size_t)tstep * 64 + b) * 512 + o] = ah;
    feedT[t] = ah;
    if (tstep == 31) outFeedf[b * 512 + o] = ah;
}

extern "C" void kernel_launch(void* const* d_in, const int* in_sizes, int n_in,
                              void* d_out, int out_size, void* d_ws, size_t ws_size,
                              hipStream_t stream) {
    const int*   toks  = (const int*)d_in[0];
    const float* ctx   = (const float*)d_in[2];
    const float* h0i   = (const float*)d_in[3];
    const float* c0i   = (const float*)d_in[4];
    const float* feedi = (const float*)d_in[5];
    const float* emb   = (const float*)d_in[6];
    const float* Wih0  = (const float*)d_in[7];
    const float* Whh0  = (const float*)d_in[8];
    const float* bih0  = (const float*)d_in[9];
    const float* bhh0  = (const float*)d_in[10];
    const float* Wih1  = (const float*)d_in[11];
    const float* Whh1  = (const float*)d_in[12];
    const float* bih1  = (const float*)d_in[13];
    const float* bhh1  = (const float*)d_in[14];
    const float* Wa    = (const float*)d_in[15];
    const float* Wout  = (const float*)d_in[16];

    // ws: partial arena 4 MB + 6 state buffers (128 KB each) = 4.75 MB
    char* ws = (char*)d_ws;
    float* Parena = (float*)(ws);                 // up to 8*2048*64*4 = 4 MB
    float* h0T   = (float*)(ws + 4194304);
    float* h1T   = (float*)(ws + 4325376);
    float* c0T   = (float*)(ws + 4456448);
    float* c1T   = (float*)(ws + 4587520);
    float* feedT = (float*)(ws + 4718592);
    float* cvecT = (float*)(ws + 4849664);

    float* out      = (float*)d_out;
    float* outMain  = out;             // [T,B,H]
    float* outAtt   = out + 1048576;   // [T,B,S]
    float* outHf    = out + 1179648;   // [L,B,H]
    float* outCf    = out + 1245184;   // [L,B,H]
    float* outFeedf = out + 1310720;   // [B,H]

    hipLaunchKernelGGL(k_init, dim3(128), dim3(256), 0, stream,
                       h0i, c0i, feedi, h0T, h1T, c0T, c1T, feedT);

    for (int t = 0; t < 32; t++) {
        // LSTM0: NG=2048, K=1536 = [emb|feed|h0], Ksplit 6 x 256
        hipLaunchKernelGGL(k_gemmp, dim3(32, 6), dim3(256), 0, stream,
                           Wih0, 1024, 1024, Whh0, 512, Parena, 2048,
                           (const float*)nullptr, feedT, h0T, emb, toks, t, 256);
        hipLaunchKernelGGL(k_cell, dim3(128), dim3(256), 0, stream,
                           Parena, 6, bih0, bhh0, h0T, c0T, outHf, outCf, t);
        // LSTM1: NG=2048, K=1024 = [h0n|h1], Ksplit 8 x 128
        hipLaunchKernelGGL(k_gemmp, dim3(32, 8), dim3(256), 0, stream,
                           Wih1, 512, 512, Whh1, 512, Parena, 2048,
                           h0T, h1T, (const float*)nullptr, emb, toks, t, 128);
        hipLaunchKernelGGL(k_cell, dim3(128), dim3(256), 0, stream,
                           Parena, 8, bih1, bhh1, h1T, c1T, outHf + 32768, outCf + 32768, t);
        // query: NG=512, K=512 = h1, Ksplit 4 x 128
        hipLaunchKernelGGL(k_gemmp, dim3(8, 4), dim3(256), 0, stream,
                           Wa, 512, 512, (const float*)nullptr, 0, Parena, 512,
                           h1T, (const float*)nullptr, (const float*)nullptr,
                           emb, toks, t, 128);
        hipLaunchKernelGGL(k_qattn, dim3(64), dim3(256), 0, stream,
                           t, ctx, Parena, 4, cvecT, outAtt);
        // out: NG=512, K=1024 = [cvec|h1], Ksplit 8 x 128
        hipLaunchKernelGGL(k_gemmp, dim3(8, 8), dim3(256), 0, stream,
                           Wout, 1024, 1024, (const float*)nullptr, 0, Parena, 512,
                           cvecT, h1T, (const float*)nullptr, emb, toks, t, 128);
        hipLaunchKernelGGL(k_outred, dim3(128), dim3(256), 0, stream,
                           t, Parena, 8, feedT, outMain, outFeedf);
    }
}